// Round 9
// baseline (996.659 us; speedup 1.0000x reference)
//
#include <hip/hip_runtime.h>
#include <math.h>

#define TT 4096
#define AA 4
#define NN 16384
#define QBQ 32
#define KBK 128
#define SS 512
#define HH 4
#define DKD 32
#define CAC 128
#define CPC 16
#define CTC 384

typedef __attribute__((ext_vector_type(8))) short bf16x8;
typedef __attribute__((ext_vector_type(4))) short s16x4;
typedef __attribute__((ext_vector_type(4))) float f32x4;

__device__ __forceinline__ float sig_(float x) { return 1.0f / (1.0f + __expf(-x)); }
__device__ __forceinline__ short f2bf(float f) {
    unsigned u = __float_as_uint(f);
    unsigned r = (u + 0x7FFFu + ((u >> 16) & 1u)) >> 16;
    return (short)r;
}
__device__ __forceinline__ float b2f(short s) {
    return __uint_as_float(((unsigned)(unsigned short)s) << 16);
}

// ---------------------------------------------------------------------------
// K0: weight prep — fp32 [K][NC] -> bf16 transposed [NC][K]
// ---------------------------------------------------------------------------
struct PEnt { const float* src; const float* rs; short* dst; int K; int NC; };
struct PTab { PEnt e[49]; };

__global__ __launch_bounds__(256) void k_prep(PTab tab)
{
    const PEnt e = tab.e[blockIdx.y];
    const int ntx = e.NC >> 5, nty = e.K >> 5, nt = ntx * nty;
    __shared__ float sm[32][33];
    const int lx = threadIdx.x & 31, ly = threadIdx.x >> 5;
    for (int t = blockIdx.x; t < nt; t += gridDim.x) {
        const int ty = t / ntx, tx = t - ty * ntx;
        #pragma unroll
        for (int j = 0; j < 4; ++j) {
            const int k = ty * 32 + ly + j * 8;
            const int n = tx * 32 + lx;
            float v = e.src[(size_t)k * e.NC + n];
            if (e.rs) v *= e.rs[k];
            sm[ly + j * 8][lx] = v;
        }
        __syncthreads();
        #pragma unroll
        for (int j = 0; j < 4; ++j) {
            const int n = tx * 32 + ly + j * 8;
            const int k = ty * 32 + lx;
            e.dst[(size_t)n * e.K + k] = f2bf(sm[lx][ly + j * 8]);
        }
        __syncthreads();
    }
}

// ---------------------------------------------------------------------------
// K1: per-atom conditioning (+ LN stats output)
// ---------------------------------------------------------------------------
__global__ __launch_bounds__(128) void k_atom_cond(
    const float* __restrict__ pos, const float* __restrict__ msk,
    const int* __restrict__ elem, const float* __restrict__ chg,
    const int* __restrict__ chars,
    const float* __restrict__ w_pos, const float* __restrict__ w_msk,
    const float* __restrict__ w_elem, const float* __restrict__ w_chg,
    const float* __restrict__ w_name,
    const float* __restrict__ w_row, const float* __restrict__ w_col,
    float* __restrict__ qsc, float* __restrict__ qact,
    short* __restrict__ qsc_bf, short* __restrict__ qn_bf,
    float* __restrict__ stats,
    float* __restrict__ rq, float* __restrict__ rk)
{
    const int n = blockIdx.x, c = threadIdx.x;
    const float p0 = pos[n*3+0], p1 = pos[n*3+1], p2 = pos[n*3+2];
    const float m = msk[n];
    const int   el = elem[n];
    const float ach = asinhf(chg[n]);
    const int c0 = chars[n*4+0], c1 = chars[n*4+1], c2 = chars[n*4+2], c3 = chars[n*4+3];

    float a = p0*w_pos[c] + p1*w_pos[CAC+c] + p2*w_pos[2*CAC+c]
            + m*w_msk[c] + w_elem[el*CAC+c] + ach*w_chg[c]
            + w_name[(c0      )*CAC+c] + w_name[( 64+c1)*CAC+c]
            + w_name[(128+c2)*CAC+c] + w_name[(192+c3)*CAC+c];
    a *= m;

    const size_t base = (size_t)n*CAC + c;
    qsc[base] = a; qact[base] = a; qsc_bf[base] = f2bf(a);

    __shared__ float red[128];
    __shared__ float sh[128];
    red[c] = a; __syncthreads();
    for (int off = 64; off > 0; off >>= 1) { if (c < off) red[c] += red[c+off]; __syncthreads(); }
    const float mu = red[0] * (1.0f/128.0f);
    __syncthreads();
    const float d = a - mu;
    red[c] = d*d; __syncthreads();
    for (int off = 64; off > 0; off >>= 1) { if (c < off) red[c] += red[c+off]; __syncthreads(); }
    const float var = red[0] * (1.0f/128.0f);
    const float rs = rsqrtf(var + 1e-5f);
    qn_bf[base] = f2bf(d * rs);
    if (c == 0) { stats[2*n] = mu; stats[2*n+1] = rs; }
    __syncthreads();
    sh[c] = fmaxf(a, 0.0f);
    __syncthreads();
    if (c < 32) {
        const float* w = (c < 16) ? w_row : w_col;
        const int cc = c & 15;
        float acc = 0.0f;
        #pragma unroll 8
        for (int r = 0; r < 128; ++r) acc += sh[r] * w[r*CPC + cc];
        if (c < 16) rq[(size_t)n*CPC + cc] = acc;
        else        rk[(size_t)n*CPC + cc] = acc;
    }
}

// ---------------------------------------------------------------------------
// K2: pair conditioning + MLP residual + pl (bf16, 3 blocks).
//     Pair output staged through LDS for coalesced 16B/lane global stores.
// ---------------------------------------------------------------------------
__global__ __launch_bounds__(256) void k_pair(
    const float* __restrict__ pos, const int* __restrict__ uid,
    const float* __restrict__ rq, const float* __restrict__ rk,
    const float* __restrict__ w_ofs, const float* __restrict__ w_dist,
    const float* __restrict__ w_pm,
    const float* __restrict__ mlp1, const float* __restrict__ mlp2,
    const float* __restrict__ mlp3,
    const float* __restrict__ wln, const float* __restrict__ wpl,
    float* __restrict__ pair, short* __restrict__ plb)
{
    __shared__ float sm1[256], sm2[256], sm3[256], sofs[48], sdist[16], smask[16];
    __shared__ float swln[16], swpl[192];
    __shared__ float st[256*17];
    const int tid = threadIdx.x;
    sm1[tid] = mlp1[tid]; sm2[tid] = mlp2[tid]; sm3[tid] = mlp3[tid];
    if (tid < 48) sofs[tid] = w_ofs[tid];
    if (tid < 16) { sdist[tid] = w_dist[tid]; smask[tid] = w_pm[tid]; swln[tid] = wln[tid]; }
    if (tid < 192) swpl[tid] = wpl[tid];
    __syncthreads();

    const int gid = blockIdx.x*256 + tid;
    const int s = gid >> 12;
    const int rem = gid & 4095;
    const int q = rem >> 7, kk = rem & 127;
    const int n = s*QBQ + q;
    int kidx = s*QBQ - 48 + kk; kidx = max(0, min(NN-1, kidx));

    const float v = (uid[n] == uid[kidx]) ? 1.0f : 0.0f;
    const float o0 = pos[n*3+0]-pos[kidx*3+0];
    const float o1 = pos[n*3+1]-pos[kidx*3+1];
    const float o2 = pos[n*3+2]-pos[kidx*3+2];
    const float sq = o0*o0 + o1*o1 + o2*o2;
    const float inv = 1.0f/(1.0f + sq);

    const float* rqp = rq + (size_t)n*CPC;
    const float* rkp = rk + (size_t)kidx*CPC;
    float rqv[16], rkv[16];
    #pragma unroll
    for (int j = 0; j < 4; ++j) {
        const float4 a = *(const float4*)(rqp + j*4);
        const float4 b = *(const float4*)(rkp + j*4);
        rqv[j*4]=a.x; rqv[j*4+1]=a.y; rqv[j*4+2]=a.z; rqv[j*4+3]=a.w;
        rkv[j*4]=b.x; rkv[j*4+1]=b.y; rkv[j*4+2]=b.z; rkv[j*4+3]=b.w;
    }

    float p[16], t1[16], t2[16];
    #pragma unroll
    for (int j = 0; j < 16; ++j)
        p[j] = v*(o0*sofs[j] + o1*sofs[16+j] + o2*sofs[32+j] + inv*sdist[j] + smask[j])
             + rqv[j] + rkv[j];
    #pragma unroll
    for (int j = 0; j < 16; ++j) {
        float acc = 0.0f;
        #pragma unroll
        for (int r = 0; r < 16; ++r) acc += fmaxf(p[r], 0.0f) * sm1[r*16+j];
        t1[j] = acc;
    }
    #pragma unroll
    for (int j = 0; j < 16; ++j) {
        float acc = 0.0f;
        #pragma unroll
        for (int r = 0; r < 16; ++r) acc += fmaxf(t1[r], 0.0f) * sm2[r*16+j];
        t2[j] = acc;
    }
    #pragma unroll
    for (int j = 0; j < 16; ++j) {
        float acc = 0.0f;
        #pragma unroll
        for (int r = 0; r < 16; ++r) acc += fmaxf(t2[r], 0.0f) * sm3[r*16+j];
        t1[j] = p[j] + acc;
    }
    // stage pair entry to LDS (17-float padded row; coalesced store later)
    #pragma unroll
    for (int j = 0; j < 16; ++j) st[tid*17 + j] = t1[j];

    // LN over 16 channels + pl projection (overlaps LDS store latency)
    float sm = 0.0f;
    #pragma unroll
    for (int j = 0; j < 16; ++j) sm += t1[j];
    const float mu = sm * (1.0f/16.0f);
    float vq = 0.0f;
    #pragma unroll
    for (int j = 0; j < 16; ++j) { const float dd = t1[j]-mu; vq += dd*dd; }
    const float rs = rsqrtf(vq*(1.0f/16.0f) + 1e-5f);
    float xn[16];
    #pragma unroll
    for (int j = 0; j < 16; ++j) xn[j] = (t1[j]-mu)*rs*swln[j];
    #pragma unroll
    for (int i = 0; i < 3; ++i) {
        #pragma unroll
        for (int h = 0; h < 4; ++h) {
            float acc = 0.0f;
            #pragma unroll
            for (int j = 0; j < 16; ++j) acc += xn[j] * swpl[j*12 + i*4 + h];
            plb[((((size_t)i*SS + s)*HH + h)*QBQ + q)*KBK + kk] = f2bf(acc);
        }
    }
    __syncthreads();
    // coalesced block write: 256 entries x 16 floats = 1024 float4, 16B/lane
    float4* bb = (float4*)(pair + (size_t)blockIdx.x*256*CPC);
    #pragma unroll
    for (int l = tid; l < 1024; l += 256) {
        const int e = l >> 2, jj = (l & 3) * 4;
        bb[l] = make_float4(st[e*17+jj], st[e*17+jj+1], st[e*17+jj+2], st[e*17+jj+3]);
    }
}

// ---------------------------------------------------------------------------
// K4: fused multi-job bf16 MFMA GEMM, MF = row-frags/wave (tile rows = MF*64).
// ---------------------------------------------------------------------------
struct FJob {
    const void* A; const void* A2;
    const float* stats; const short* G; const short* S;
    const short* Bt; const float* bias;
    float* outF; short* outB;
    const short* gate; float* resid; float* ostats;
    int K; int ostride; int amode; int emode;
};
struct FJobs { FJob j[8]; };

template<int MF>
__global__ __launch_bounds__(256) void k_mmf(FJobs jobs)
{
    __shared__ short As[MF*64*64];
    __shared__ short Bs[128*64];
    const FJob J = jobs.j[blockIdx.y];
    const int tid = threadIdx.x;
    const int wave = tid >> 6, lane = tid & 63;
    const int l15 = lane & 15, l4 = lane >> 4;
    const int row0 = blockIdx.x * (MF*64);
    const int K = J.K;

    f32x4 acc[MF][8];
    #pragma unroll
    for (int m = 0; m < MF; ++m)
        #pragma unroll
        for (int n = 0; n < 8; ++n) acc[m][n] = (f32x4){0.f,0.f,0.f,0.f};

    for (int k0 = 0; k0 < K; k0 += 64) {
        #pragma unroll
        for (int j = 0; j < MF*2; ++j) {
            const int u = tid + j*256;
            const int r = u >> 3, ug = u & 7;
            const int row = row0 + r;
            const size_t ao = (size_t)row*K + k0 + ug*8;
            bf16x8 av;
            if (J.amode == 0) {
                av = *(const bf16x8*)((const short*)J.A + ao);
            } else if (J.amode == 2) {
                const float* Ao = (const float*)J.A;
                const float* Ag = (const float*)J.A2;
                const float4 oa = *(const float4*)(Ao + ao);
                const float4 ob = *(const float4*)(Ao + ao + 4);
                const float4 ga = *(const float4*)(Ag + ao);
                const float4 gb = *(const float4*)(Ag + ao + 4);
                av[0]=f2bf(oa.x*ga.x); av[1]=f2bf(oa.y*ga.y); av[2]=f2bf(oa.z*ga.z); av[3]=f2bf(oa.w*ga.w);
                av[4]=f2bf(ob.x*gb.x); av[5]=f2bf(ob.y*gb.y); av[6]=f2bf(ob.z*gb.z); av[7]=f2bf(ob.w*gb.w);
            } else {
                const float* Af = (const float*)J.A;
                const float4 a0 = *(const float4*)(Af + ao);
                const float4 a1 = *(const float4*)(Af + ao + 4);
                av[0]=f2bf(a0.x); av[1]=f2bf(a0.y); av[2]=f2bf(a0.z); av[3]=f2bf(a0.w);
                av[4]=f2bf(a1.x); av[5]=f2bf(a1.y); av[6]=f2bf(a1.z); av[7]=f2bf(a1.w);
            }
            *(bf16x8*)&As[r*64 + ((ug ^ (r & 7)) * 8)] = av;
        }
        #pragma unroll
        for (int j = 0; j < 4; ++j) {
            const int u = tid + j*256;
            const int r = u >> 3, ug = u & 7;
            *(bf16x8*)&Bs[r*64 + ((ug ^ (r & 7)) * 8)] =
                *(const bf16x8*)(J.Bt + (size_t)r*K + k0 + ug*8);
        }
        __syncthreads();
        #pragma unroll
        for (int ks = 0; ks < 2; ++ks) {
            bf16x8 af[MF], bfr[8];
            #pragma unroll
            for (int m = 0; m < MF; ++m) {
                const int r = wave*(16*MF) + m*16 + l15;
                af[m] = *(const bf16x8*)&As[r*64 + (((ks*4 + l4) ^ (r & 7)) * 8)];
            }
            #pragma unroll
            for (int n = 0; n < 8; ++n) {
                const int c = n*16 + l15;
                bfr[n] = *(const bf16x8*)&Bs[c*64 + (((ks*4 + l4) ^ (c & 7)) * 8)];
            }
            #pragma unroll
            for (int m = 0; m < MF; ++m)
                #pragma unroll
                for (int n = 0; n < 8; ++n)
                    acc[m][n] = __builtin_amdgcn_mfma_f32_16x16x32_bf16(af[m], bfr[n], acc[m][n], 0, 0, 0);
        }
        __syncthreads();
    }

    if (J.emode == 3) {
        #pragma unroll
        for (int m = 0; m < MF; ++m) {
            #pragma unroll
            for (int reg = 0; reg < 4; ++reg) {
                const int row = row0 + wave*(16*MF) + m*16 + l4*4 + reg;
                float s = 0.0f, q = 0.0f;
                #pragma unroll
                for (int n = 0; n < 8; ++n) {
                    const int col = n*16 + l15;
                    const size_t off = (size_t)row*CAC + col;
                    const float v = J.resid[off] + acc[m][n][reg] * b2f(J.gate[off]);
                    J.resid[off] = v;
                    s += v; q += v*v;
                }
                #pragma unroll
                for (int msk = 1; msk < 16; msk <<= 1) {
                    s += __shfl_xor(s, msk, 64);
                    q += __shfl_xor(q, msk, 64);
                }
                if (l15 == 0) {
                    const float mu = s * (1.0f/128.0f);
                    const float var = q * (1.0f/128.0f) - mu*mu;
                    J.ostats[2*row]   = mu;
                    J.ostats[2*row+1] = rsqrtf(var + 1e-5f);
                }
            }
        }
    } else {
        float bval[8];
        #pragma unroll
        for (int n = 0; n < 8; ++n) bval[n] = 0.0f;
        if (J.bias) {
            #pragma unroll
            for (int n = 0; n < 8; ++n) bval[n] = J.bias[n*16 + l15];
        }
        const int epi = J.emode;
        #pragma unroll
        for (int m = 0; m < MF; ++m) {
            #pragma unroll
            for (int n = 0; n < 8; ++n) {
                const int col = n*16 + l15;
                #pragma unroll
                for (int reg = 0; reg < 4; ++reg) {
                    const int row = row0 + wave*(16*MF) + m*16 + l4*4 + reg;
                    float v = acc[m][n][reg] + bval[n];
                    if (epi == 1) v = sig_(v);
                    if (epi == 2) v = fmaxf(v, 0.0f);
                    if (J.outB) J.outB[(size_t)row*J.ostride + col] = f2bf(v);
                    else        J.outF[(size_t)row*J.ostride + col] = v;
                }
            }
        }
    }
}

// ---------------------------------------------------------------------------
// K4b: q/k/v/g projections, dual-B: A staged once per side (adaLN fused).
//   blockIdx.y==0: A=adaLN(Gq,Sq); outs w_q = A@wq + bq, w_g = sig(A@wg)
//   blockIdx.y==1: A=adaLN(Gk,Sk); outs w_k = A@wk,      w_v = A@wv
// ---------------------------------------------------------------------------
__global__ __launch_bounds__(256) void k_mm_qkvg(
    const float* __restrict__ qact, const float* __restrict__ stats,
    const short* __restrict__ Gq, const short* __restrict__ Sq,
    const short* __restrict__ Gk, const short* __restrict__ Sk,
    const short* __restrict__ Btq, const short* __restrict__ Btg,
    const short* __restrict__ Btk, const short* __restrict__ Btv,
    const float* __restrict__ bq,
    float* __restrict__ w_q, float* __restrict__ w_k,
    float* __restrict__ w_v, float* __restrict__ w_g)
{
    __shared__ short As[128*64];
    __shared__ short B1s[128*64];
    __shared__ short B2s[128*64];
    const int tid = threadIdx.x;
    const int wave = tid >> 6, lane = tid & 63;
    const int l15 = lane & 15, l4 = lane >> 4;
    const int row0 = blockIdx.x * 128;
    const bool qside = (blockIdx.y == 0);
    const short* G  = qside ? Gq : Gk;
    const short* S  = qside ? Sq : Sk;
    const short* B1 = qside ? Btq : Btk;
    const short* B2 = qside ? Btg : Btv;
    float* O1 = qside ? w_q : w_k;
    float* O2 = qside ? w_g : w_v;

    f32x4 acc1[2][8], acc2[2][8];
    #pragma unroll
    for (int m = 0; m < 2; ++m)
        #pragma unroll
        for (int n = 0; n < 8; ++n) {
            acc1[m][n] = (f32x4){0.f,0.f,0.f,0.f};
            acc2[m][n] = (f32x4){0.f,0.f,0.f,0.f};
        }

    for (int k0 = 0; k0 < 128; k0 += 64) {
        #pragma unroll
        for (int j = 0; j < 4; ++j) {
            const int u = tid + j*256;
            const int r = u >> 3, ug = u & 7;
            const int row = row0 + r;
            const size_t ao = (size_t)row*CAC + k0 + ug*8;
            const float4 a0 = *(const float4*)(qact + ao);
            const float4 a1 = *(const float4*)(qact + ao + 4);
            const float mu = stats[2*row], rs = stats[2*row+1];
            const s16x4 g0 = *(const s16x4*)(G + ao), g1 = *(const s16x4*)(G + ao + 4);
            const s16x4 s0 = *(const s16x4*)(S + ao), s1 = *(const s16x4*)(S + ao + 4);
            const float x[8] = {a0.x,a0.y,a0.z,a0.w,a1.x,a1.y,a1.z,a1.w};
            bf16x8 av;
            #pragma unroll
            for (int t = 0; t < 4; ++t) {
                av[t]   = f2bf(b2f(g0[t])*((x[t]  -mu)*rs) + b2f(s0[t]));
                av[t+4] = f2bf(b2f(g1[t])*((x[t+4]-mu)*rs) + b2f(s1[t]));
            }
            const int sw = (ug ^ (r & 7)) * 8;
            *(bf16x8*)&As[r*64 + sw] = av;
            const size_t bo = (size_t)r*CAC + k0 + ug*8;
            *(bf16x8*)&B1s[r*64 + sw] = *(const bf16x8*)(B1 + bo);
            *(bf16x8*)&B2s[r*64 + sw] = *(const bf16x8*)(B2 + bo);
        }
        __syncthreads();
        #pragma unroll
        for (int ks = 0; ks < 2; ++ks) {
            bf16x8 af[2], b1f[8], b2f_[8];
            #pragma unroll
            for (int m = 0; m < 2; ++m) {
                const int r = wave*32 + m*16 + l15;
                af[m] = *(const bf16x8*)&As[r*64 + (((ks*4 + l4) ^ (r & 7)) * 8)];
            }
            #pragma unroll
            for (int n = 0; n < 8; ++n) {
                const int c = n*16 + l15;
                const int sw = ((ks*4 + l4) ^ (c & 7)) * 8;
                b1f[n] = *(const bf16x8*)&B1s[c*64 + sw];
                b2f_[n] = *(const bf16x8*)&B2s[c*64 + sw];
            }
            #pragma unroll
            for (int m = 0; m < 2; ++m)
                #pragma unroll
                for (int n = 0; n < 8; ++n) {
                    acc1[m][n] = __builtin_amdgcn_mfma_f32_16x16x32_bf16(af[m], b1f[n], acc1[m][n], 0, 0, 0);
                    acc2[m][n] = __builtin_amdgcn_mfma_f32_16x16x32_bf16(af[m], b2f_[n], acc2[m][n], 0, 0, 0);
                }
        }
        __syncthreads();
    }

    #pragma unroll
    for (int m = 0; m < 2; ++m)
        #pragma unroll
        for (int n = 0; n < 8; ++n) {
            const int col = n*16 + l15;
            const float bv = qside ? bq[col] : 0.0f;
            #pragma unroll
            for (int reg = 0; reg < 4; ++reg) {
                const int row = row0 + wave*32 + m*16 + l4*4 + reg;
                O1[(size_t)row*CAC + col] = acc1[m][n][reg] + bv;
                const float v2 = acc2[m][n][reg];
                O2[(size_t)row*CAC + col] = qside ? sig_(v2) : v2;
            }
        }
}

// ---------------------------------------------------------------------------
// K4c: SwiGLU GEMM, 128-col pair tile (reads glu1&glu2 same cols):
//      x = adaLN(Gt,St); hs = bf16(silu(x@glu1)*(x@glu2)). grid (128,2).
// ---------------------------------------------------------------------------
__global__ __launch_bounds__(256) void k_mm_glu(
    const float* __restrict__ qact, const float* __restrict__ stats,
    const short* __restrict__ Gt, const short* __restrict__ St,
    const short* __restrict__ B1t, const short* __restrict__ B2t,
    short* __restrict__ out)
{
    __shared__ short As[128*64];
    __shared__ short B1s[128*64];
    __shared__ short B2s[128*64];
    const int tid = threadIdx.x;
    const int wave = tid >> 6, lane = tid & 63;
    const int l15 = lane & 15, l4 = lane >> 4;
    const int row0 = blockIdx.x * 128;
    const int col0 = blockIdx.y * 128;

    f32x4 acc1[2][8], acc2[2][8];
    #pragma unroll
    for (int m = 0; m < 2; ++m)
        #pragma unroll
        for (int n = 0; n < 8; ++n) {
            acc1[m][n] = (f32x4){0.f,0.f,0.f,0.f};
            acc2[m][n] = (f32x4){0.f,0.f,0.f,0.f};
        }

    for (int k0 = 0; k0 < 128; k0 += 64) {
        #pragma unroll
        for (int j = 0; j < 4; ++j) {
            const int u = tid + j*256;
            const int r = u >> 3, ug = u & 7;
            const int row = row0 + r;
            const size_t ao = (size_t)row*CAC + k0 + ug*8;
            const float4 a0 = *(const float4*)(qact + ao);
            const float4 a1 = *(const float4*)(qact + ao + 4);
            const float mu = stats[2*row], rs = stats[2*row+1];
            const s16x4 g0 = *(const s16x4*)(Gt + ao), g1 = *(const s16x4*)(Gt + ao + 4);
            const s16x4 s0 = *(const s16x4*)(St + ao), s1 = *(const s16x4*)(St + ao + 4);
            const float x[8] = {a0.x,a0.y,a0.z,a0.w,a1.x,a1.y,a1.z,a1.w};
            bf16x8 av;
            #pragma unroll
            for (int t = 0; t < 4; ++t) {
                av[t]   = f2bf(b2f(g0[t])*((x[t]  -mu)*rs) + b2f(s0[t]));
                av[t+4] = f2bf(b2f(g1[t])*((x[t+4]-mu)*rs) + b2f(s1[t]));
            }
            const int sw = (ug ^ (r & 7)) * 8;
            *(bf16x8*)&As[r*64 + sw] = av;
            const size_t bo = (size_t)(col0 + r)*CAC + k0 + ug*8;
            *(bf16x8*)&B1s[r*64 + sw] = *(const bf16x8*)(B1t + bo);
            *(bf16x8*)&B2s[r*64 + sw] = *(const bf16x8*)(B2t + bo);
        }
        __syncthreads();
        #pragma unroll
        for (int ks = 0; ks < 2; ++ks) {
            bf16x8 af[2], b1f[8], b2f_[8];
            #pragma unroll
            for (int m = 0; m < 2; ++m) {
                const int r = wave*32 + m*16 + l15;
                af[m] = *(const bf16x8*)&As[r*64 + (((ks*4 + l4) ^ (r & 7)) * 8)];
            }
            #pragma unroll
            for (int n = 0; n < 8; ++n) {
                const int c = n*16 + l15;
                const int sw = ((ks*4 + l4) ^ (c & 7)) * 8;
                b1f[n] = *(const bf16x8*)&B1s[c*64 + sw];
                b2f_[n] = *(const bf16x8*)&B2s[c*64 + sw];
            }
            #pragma unroll
            for (int m = 0; m < 2; ++m)
                #pragma unroll
                for (int n = 0; n < 8; ++n) {
                    acc1[m][n] = __builtin_amdgcn_mfma_f32_16x16x32_bf16(af[m], b1f[n], acc1[m][n], 0, 0, 0);
                    acc2[m][n] = __builtin_amdgcn_mfma_f32_16x16x32_bf16(af[m], b2f_[n], acc2[m][n], 0, 0, 0);
                }
        }
        __syncthreads();
    }

    #pragma unroll
    for (int m = 0; m < 2; ++m)
        #pragma unroll
        for (int n = 0; n < 8; ++n) {
            const int col = col0 + n*16 + l15;
            #pragma unroll
            for (int reg = 0; reg < 4; ++reg) {
                const int row = row0 + wave*32 + m*16 + l4*4 + reg;
                const float a1 = acc1[m][n][reg];
                out[(size_t)row*256 + col] = f2bf(a1 * sig_(a1) * acc2[m][n][reg]);
            }
        }
}

// ---------------------------------------------------------------------------
// K5: flash attention (pl in bf16)
// ---------------------------------------------------------------------------
__global__ __launch_bounds__(512) void k_attn2(
    const float* __restrict__ qh, const float* __restrict__ kh,
    const float* __restrict__ vh, const short* __restrict__ pls,
    float* __restrict__ oh)
{
    __shared__ float sm_m[256], sm_l[256], sm_acc[256*17];
    const int s = blockIdx.x, tid = threadIdx.x;
    const int kh2 = tid >> 8;
    const int h = (tid >> 6) & 3;
    const int q = (tid >> 1) & 31;
    const int dh = tid & 1;
    const int n0 = s*QBQ;
    const int kbase = n0 - 48 + kh2*64;
    const float SCALE = 0.17677669529663687f;

    float qr[32];
    {
        const float* qp = qh + (size_t)(n0+q)*CAC + h*DKD;
        #pragma unroll
        for (int j = 0; j < 8; ++j) {
            const float4 v4 = *(const float4*)(qp + j*4);
            qr[j*4]=v4.x*SCALE; qr[j*4+1]=v4.y*SCALE; qr[j*4+2]=v4.z*SCALE; qr[j*4+3]=v4.w*SCALE;
        }
    }
    const short* plp = pls + (((size_t)s*HH + h)*QBQ + q)*KBK + kh2*64;

    float m = -1e30f, l = 0.0f;
    float acc[16];
    #pragma unroll
    for (int j = 0; j < 16; ++j) acc[j] = 0.0f;

    for (int kb4 = 0; kb4 < 16; ++kb4) {
        const s16x4 p4 = *(const s16x4*)(plp + kb4*4);
        float pv[4];
        #pragma unroll
        for (int j = 0; j < 4; ++j) pv[j] = b2f(p4[j]);
        #pragma unroll
        for (int j = 0; j < 4; ++j) {
            const int kb = kb4*4 + j;
            int kidx = kbase + kb; kidx = max(0, min(NN-1, kidx));
            const float* kp = kh + (size_t)kidx*CAC + h*DKD;
            float dot = 0.0f;
            #pragma unroll
            for (int jj = 0; jj < 8; ++jj) {
                const float4 kv = *(const float4*)(kp + jj*4);
                dot += qr[jj*4]*kv.x + qr[jj*4+1]*kv.y + qr[jj*4+2]*kv.z + qr[jj*4+3]*kv.w;
            }
            const float sv = dot + pv[j];
            if (sv > m) {
                const float corr = __expf(m - sv);
                l *= corr;
                #pragma unroll
                for (int d = 0; d < 16; ++d) acc[d] *= corr;
                m = sv;
            }
            const float w = __expf(sv - m);
            l += w;
            const float* vp = vh + (size_t)kidx*CAC + h*DKD + dh*16;
            #pragma unroll
            for (int jj = 0; jj < 4; ++jj) {
                const float4 vv = *(const float4*)(vp + jj*4);
                acc[jj*4]   = fmaf(w, vv.x, acc[jj*4]);
                acc[jj*4+1] = fmaf(w, vv.y, acc[jj*4+1]);
                acc[jj*4+2] = fmaf(w, vv.z, acc[jj*4+2]);
                acc[jj*4+3] = fmaf(w, vv.w, acc[jj*4+3]);
            }
        }
    }

    const int part = tid & 255;
    if (kh2 == 1) {
        sm_m[part] = m; sm_l[part] = l;
        #pragma unroll
        for (int j = 0; j < 16; ++j) sm_acc[part*17 + j] = acc[j];
    }
    __syncthreads();
    if (kh2 == 0) {
        const float m2 = sm_m[part], l2 = sm_l[part];
        const float mm = fmaxf(m, m2);
        const float c1 = __expf(m - mm), c2 = __expf(m2 - mm);
        const float inv = 1.0f / (l*c1 + l2*c2);
        float* op = oh + (size_t)(n0+q)*CAC + h*DKD + dh*16;
        #pragma unroll
        for (int jj = 0; jj < 4; ++jj) {
            float o0 = (acc[jj*4  ]*c1 + sm_acc[part*17+jj*4  ]*c2) * inv;
            float o1 = (acc[jj*4+1]*c1 + sm_acc[part*17+jj*4+1]*c2) * inv;
            float o2 = (acc[jj*4+2]*c1 + sm_acc[part*17+jj*4+2]*c2) * inv;
            float o3 = (acc[jj*4+3]*c1 + sm_acc[part*17+jj*4+3]*c2) * inv;
            *(float4*)op = make_float4(o0,o1,o2,o3);
            op += 4;
        }
    }
}

__global__ __launch_bounds__(256) void k_token_reduce(
    const float* __restrict__ tok, const float* __restrict__ msk, float* __restrict__ out)
{
    const int gid = blockIdx.x*256 + threadIdx.x;
    const int t = gid / CTC, c = gid - t*CTC;
    float num = 0.0f, den = 0.0f;
    #pragma unroll
    for (int a = 0; a < AA; ++a) {
        const float mv = msk[t*AA + a];
        num += tok[(size_t)(t*AA+a)*CTC + c] * mv;
        den += mv;
    }
    out[gid] = num / fmaxf(den, 1e-10f);
}

// ---------------------------------------------------------------------------
// launch
// ---------------------------------------------------------------------------
static inline FJob fj0() { FJob j{}; return j; }

extern "C" void kernel_launch(void* const* d_in, const int* in_sizes, int n_in,
                              void* d_out, int out_size, void* d_ws, size_t ws_size,
                              hipStream_t stream)
{
    const float* positions = (const float*)d_in[0];
    const float* maskp     = (const float*)d_in[1];
    const int*   element   = (const int*  )d_in[2];
    const float* charge    = (const float*)d_in[3];
    const int*   chars     = (const int*  )d_in[4];
    const int*   uid       = (const int*  )d_in[5];
    const float* w_ref_pos      = (const float*)d_in[6];
    const float* w_ref_mask     = (const float*)d_in[7];
    const float* w_ref_element  = (const float*)d_in[8];
    const float* w_ref_charge   = (const float*)d_in[9];
    const float* w_ref_atom_name= (const float*)d_in[10];
    const float* w_s2p_row      = (const float*)d_in[11];
    const float* w_s2p_col      = (const float*)d_in[12];
    const float* w_pair_offsets = (const float*)d_in[13];
    const float* w_pair_dist    = (const float*)d_in[14];
    const float* w_pair_mask    = (const float*)d_in[15];
    const float* w_pair_mlp1    = (const float*)d_in[16];
    const float* w_pair_mlp2    = (const float*)d_in[17];
    const float* w_pair_mlp3    = (const float*)d_in[18];
    const float* w_pair_ln      = (const float*)d_in[19];
    const float* w_pair_logits  = (const float*)d_in[20];
    const float* aq_lnw = (const float*)d_in[21];
    const float* aq_gw  = (const float*)d_in[22];
    const float* aq_gb  = (const float*)d_in[23];
    const float* aq_sw  = (const float*)d_in[24];
    const float* ak_lnw = (const float*)d_in[25];
    const float* ak_gw  = (const float*)d_in[26];
    const float* ak_gb  = (const float*)d_in[27];
    const float* ak_sw  = (const float*)d_in[28];
    const float* wq     = (const float*)d_in[29];
    const float* bq     = (const float*)d_in[30];
    const float* wk     = (const float*)d_in[31];
    const float* wv     = (const float*)d_in[32];
    const float* wg     = (const float*)d_in[33];
    const float* azi_w  = (const float*)d_in[34];
    const float* azi_cw = (const float*)d_in[35];
    const float* azi_cb = (const float*)d_in[36];
    const float* t_lnw  = (const float*)d_in[37];
    const float* t_gw   = (const float*)d_in[38];
    const float* t_gb   = (const float*)d_in[39];
    const float* t_sw   = (const float*)d_in[40];
    const float* glu1   = (const float*)d_in[41];
    const float* glu2   = (const float*)d_in[42];
    const float* t_azi_w  = (const float*)d_in[43];
    const float* t_azi_cw = (const float*)d_in[44];
    const float* t_azi_cb = (const float*)d_in[45];
    const float* w_project= (const float*)d_in[46];

    float* token_o = (float*)d_out;
    float* qact = token_o + 1572864;
    float* qsc  = token_o + 3670016;
    float* pair = token_o + 5767168;

    char* W = (char*)d_ws;
    short* pl_bf   = (short*)(W);                 // 50,331,648
    short* wbf     = (short*)(W + 50331648);      //  2,097,152
    short* qn_bf   = (short*)(W + 52428800);      //  4,194,304
    short* qsc_bf  = (short*)(W + 56623104);      //  4,194,304
    float* stats   = (float*)(W + 60817408);      //    131,072
    short* Gq_bf   = (short*)(W + 60948480);
    short* Sq_bf   = (short*)(W + 65142784);
    short* Gk_bf   = (short*)(W + 69337088);
    short* Sk_bf   = (short*)(W + 73531392);
    short* Gt_bf   = (short*)(W + 77725696);
    short* St_bf   = (short*)(W + 81920000);
    short* Ag_bf   = (short*)(W + 86114304);
    short* Tg_bf   = (short*)(W + 90308608);
    float* w_q     = (float*)(W + 94502912);
    float* w_k     = (float*)(W + 102891520);
    float* w_v     = (float*)(W + 111280128);
    float* w_g     = (float*)(W + 119668736);
    float* w_o     = (float*)(W + 128057344);
    short* hs_bf   = (short*)(W + 136445952);
    float* rq      = (float*)(W + 144834560);
    float* rk      = (float*)(W + 145883136);
    float* tok = w_q;

    (void)in_sizes; (void)n_in; (void)out_size; (void)ws_size;

    const size_t LSTR = 311296;
    const size_t oGQ=0, oSQ=16384, oGK=32768, oSK=49152, oGT=65536, oST=81920,
                 oWQ=98304, oWK=114688, oWV=131072, oWG=147456, oAZ=163840,
                 oACW=180224, oTCW=196608, oG1=212992, oG2=245760, oTAW=278528;
    const size_t oPROJ = 3*LSTR;

    {   // ---- weight prep ----
        PTab tab{};
        int e = 0;
        for (int i = 0; i < 3; ++i) {
            short* L = wbf + (size_t)i*LSTR;
            const size_t oM = (size_t)i*CAC*CAC, oV = (size_t)i*CAC, oGL = (size_t)i*CAC*2*CAC;
            tab.e[e++] = {aq_gw+oM,  aq_lnw+oV, L+oGQ,  128, 128};
            tab.e[e++] = {aq_sw+oM,  aq_lnw+oV, L+oSQ,  128, 128};
            tab.e[e++] = {ak_gw+oM,  ak_lnw+oV, L+oGK,  128, 128};
            tab.e[e++] = {ak_sw+oM,  ak_lnw+oV, L+oSK,  128, 128};
            tab.e[e++] = {t_gw+oM,   t_lnw+oV,  L+oGT,  128, 128};
            tab.e[e++] = {t_sw+oM,   t_lnw+oV,  L+oST,  128, 128};
            tab.e[e++] = {wq+oM,     nullptr,   L+oWQ,  128, 128};
            tab.e[e++] = {wk+oM,     nullptr,   L+oWK,  128, 128};
            tab.e[e++] = {wv+oM,     nullptr,   L+oWV,  128, 128};
            tab.e[e++] = {wg+oM,     nullptr,   L+oWG,  128, 128};
            tab.e[e++] = {azi_w+oM,  nullptr,   L+oAZ,  128, 128};
            tab.e[e++] = {azi_cw+oM, nullptr,   L+oACW, 128, 128};
            tab.e[e++] = {t_azi_cw+oM,nullptr,  L+oTCW, 128, 128};
            tab.e[e++] = {glu1+oGL,  nullptr,   L+oG1,  128, 256};
            tab.e[e++] = {glu2+oGL,  nullptr,   L+oG2,  128, 256};
            tab.e[e++] = {t_azi_w+oGL,nullptr,  L+oTAW, 256, 128};
        }
        tab.e[e++] = {w_project, nullptr, wbf+oPROJ, 128, 384};
        k_prep<<<dim3(48, 49), 256, 0, stream>>>(tab);
    }

    k_atom_cond<<<NN, 128, 0, stream>>>(positions, maskp, element, charge, chars,
        w_ref_pos, w_ref_mask, w_ref_element, w_ref_charge, w_ref_atom_name,
        w_s2p_row, w_s2p_col, qsc, qact, qsc_bf, qn_bf, stats, rq, rk);

    k_pair<<<(SS*QBQ*KBK)/256, 256, 0, stream>>>(positions, uid, rq, rk,
        w_pair_offsets, w_pair_dist, w_pair_mask, w_pair_mlp1, w_pair_mlp2, w_pair_mlp3,
        w_pair_ln, w_pair_logits, pair, pl_bf);

    for (int i = 0; i < 3; ++i) {
        short* L = wbf + (size_t)i*LSTR;
        const size_t oV = (size_t)i*CAC;

        {   // cond-only GEMMs (8 jobs, amode0): gates for this layer
            FJobs js{};
            struct { const short* A; const short* Bt; const float* bias; short* out; int em; } cfg[8] = {
                {qn_bf,  L+oGQ,  aq_gb+oV,    Gq_bf, 1}, {qn_bf,  L+oSQ,  nullptr, Sq_bf, 0},
                {qn_bf,  L+oGK,  ak_gb+oV,    Gk_bf, 1}, {qn_bf,  L+oSK,  nullptr, Sk_bf, 0},
                {qn_bf,  L+oGT,  t_gb+oV,     Gt_bf, 1}, {qn_bf,  L+oST,  nullptr, St_bf, 0},
                {qsc_bf, L+oACW, azi_cb+oV,   Ag_bf, 1}, {qsc_bf, L+oTCW, t_azi_cb+oV, Tg_bf, 1}};
            for (int jn = 0; jn < 8; ++jn) {
                FJob j = fj0();
                j.A = cfg[jn].A; j.Bt = cfg[jn].Bt; j.bias = cfg[jn].bias;
                j.outB = cfg[jn].out; j.K = 128; j.ostride = 128;
                j.amode = 0; j.emode = cfg[jn].em;
                js.j[jn] = j;
            }
            k_mmf<2><<<dim3(128, 8), 256, 0, stream>>>(js);
        }
        // q,k,v,g projections: dual-B, adaLN A staged once per side
        k_mm_qkvg<<<dim3(128, 2), 256, 0, stream>>>(qact, stats,
            Gq_bf, Sq_bf, Gk_bf, Sk_bf, L+oWQ, L+oWG, L+oWK, L+oWV,
            bq+oV, w_q, w_k, w_v, w_g);
        k_attn2<<<SS, 512, 0, stream>>>(w_q, w_k, w_v, pl_bf + (size_t)i*8388608, w_o);
        {   // o-projection: A=o*g (amode2); epilogue residual+stats (emode3)
            FJobs js{};
            FJob j = fj0();
            j.A = w_o; j.A2 = w_g; j.Bt = L+oAZ;
            j.gate = Ag_bf; j.resid = qact; j.ostats = stats;
            j.K = 128; j.ostride = 128; j.amode = 2; j.emode = 3;
            js.j[0] = j;
            k_mmf<1><<<dim3(256, 1), 256, 0, stream>>>(js);
        }
        // SwiGLU (adaLN staging + silu*mul epilogue), 128-col pair tiles
        k_mm_glu<<<dim3(128, 2), 256, 0, stream>>>(qact, stats, Gt_bf, St_bf, L+oG1, L+oG2, hs_bf);
        {   // transition out-projection (K=256); epilogue residual+stats
            FJobs js{};
            FJob j = fj0();
            j.A = hs_bf; j.Bt = L+oTAW;
            j.gate = Tg_bf; j.resid = qact; j.ostats = stats;
            j.K = 256; j.ostride = 128; j.amode = 0; j.emode = 3;
            js.j[0] = j;
            k_mmf<1><<<dim3(256, 1), 256, 0, stream>>>(js);
        }
    }

    {   // token projection: A = fp32 qact cast inline (amode3), 3 col slices
        FJobs js{};
        for (int c = 0; c < 3; ++c) {
            FJob j = fj0();
            j.A = qact; j.Bt = wbf + oPROJ + (size_t)c*16384;
            j.outF = tok + c*128;
            j.K = 128; j.ostride = 384; j.amode = 3; j.emode = 2;
            js.j[c] = j;
        }
        k_mmf<1><<<dim3(256, 3), 256, 0, stream>>>(js);
    }
    k_token_reduce<<<(TT*CTC)/256, 256, 0, stream>>>(tok, maskp, token_o);
}

// Round 11
// 851.275 us; speedup vs baseline: 1.1708x; 1.1708x over previous
//
#include <hip/hip_runtime.h>
#include <math.h>

#define TT 4096
#define AA 4
#define NN 16384
#define QBQ 32
#define KBK 128
#define SS 512
#define HH 4
#define DKD 32
#define CAC 128
#define CPC 16
#define CTC 384

typedef __attribute__((ext_vector_type(8))) short bf16x8;
typedef __attribute__((ext_vector_type(4))) short s16x4;
typedef __attribute__((ext_vector_type(4))) float f32x4;

__device__ __forceinline__ float sig_(float x) { return 1.0f / (1.0f + __expf(-x)); }
__device__ __forceinline__ short f2bf(float f) {
    unsigned u = __float_as_uint(f);
    unsigned r = (u + 0x7FFFu + ((u >> 16) & 1u)) >> 16;
    return (short)r;
}
__device__ __forceinline__ float b2f(short s) {
    return __uint_as_float(((unsigned)(unsigned short)s) << 16);
}

// ---------------------------------------------------------------------------
// K0: weight prep — fp32 [K][NC] -> bf16 transposed [NC][K]
// ---------------------------------------------------------------------------
struct PEnt { const float* src; const float* rs; short* dst; int K; int NC; };
struct PTab { PEnt e[49]; };

__global__ __launch_bounds__(256) void k_prep(PTab tab)
{
    const PEnt e = tab.e[blockIdx.y];
    const int ntx = e.NC >> 5, nty = e.K >> 5, nt = ntx * nty;
    __shared__ float sm[32][33];
    const int lx = threadIdx.x & 31, ly = threadIdx.x >> 5;
    for (int t = blockIdx.x; t < nt; t += gridDim.x) {
        const int ty = t / ntx, tx = t - ty * ntx;
        #pragma unroll
        for (int j = 0; j < 4; ++j) {
            const int k = ty * 32 + ly + j * 8;
            const int n = tx * 32 + lx;
            float v = e.src[(size_t)k * e.NC + n];
            if (e.rs) v *= e.rs[k];
            sm[ly + j * 8][lx] = v;
        }
        __syncthreads();
        #pragma unroll
        for (int j = 0; j < 4; ++j) {
            const int n = tx * 32 + ly + j * 8;
            const int k = ty * 32 + lx;
            e.dst[(size_t)n * e.K + k] = f2bf(sm[lx][ly + j * 8]);
        }
        __syncthreads();
    }
}

// ---------------------------------------------------------------------------
// K1: per-atom conditioning (+ LN stats output)
// ---------------------------------------------------------------------------
__global__ __launch_bounds__(128) void k_atom_cond(
    const float* __restrict__ pos, const float* __restrict__ msk,
    const int* __restrict__ elem, const float* __restrict__ chg,
    const int* __restrict__ chars,
    const float* __restrict__ w_pos, const float* __restrict__ w_msk,
    const float* __restrict__ w_elem, const float* __restrict__ w_chg,
    const float* __restrict__ w_name,
    const float* __restrict__ w_row, const float* __restrict__ w_col,
    float* __restrict__ qsc, float* __restrict__ qact,
    short* __restrict__ qsc_bf, short* __restrict__ qn_bf,
    float* __restrict__ stats,
    float* __restrict__ rq, float* __restrict__ rk)
{
    const int n = blockIdx.x, c = threadIdx.x;
    const float p0 = pos[n*3+0], p1 = pos[n*3+1], p2 = pos[n*3+2];
    const float m = msk[n];
    const int   el = elem[n];
    const float ach = asinhf(chg[n]);
    const int c0 = chars[n*4+0], c1 = chars[n*4+1], c2 = chars[n*4+2], c3 = chars[n*4+3];

    float a = p0*w_pos[c] + p1*w_pos[CAC+c] + p2*w_pos[2*CAC+c]
            + m*w_msk[c] + w_elem[el*CAC+c] + ach*w_chg[c]
            + w_name[(c0      )*CAC+c] + w_name[( 64+c1)*CAC+c]
            + w_name[(128+c2)*CAC+c] + w_name[(192+c3)*CAC+c];
    a *= m;

    const size_t base = (size_t)n*CAC + c;
    qsc[base] = a; qact[base] = a; qsc_bf[base] = f2bf(a);

    __shared__ float red[128];
    __shared__ float sh[128];
    red[c] = a; __syncthreads();
    for (int off = 64; off > 0; off >>= 1) { if (c < off) red[c] += red[c+off]; __syncthreads(); }
    const float mu = red[0] * (1.0f/128.0f);
    __syncthreads();
    const float d = a - mu;
    red[c] = d*d; __syncthreads();
    for (int off = 64; off > 0; off >>= 1) { if (c < off) red[c] += red[c+off]; __syncthreads(); }
    const float var = red[0] * (1.0f/128.0f);
    const float rs = rsqrtf(var + 1e-5f);
    qn_bf[base] = f2bf(d * rs);
    if (c == 0) { stats[2*n] = mu; stats[2*n+1] = rs; }
    __syncthreads();
    sh[c] = fmaxf(a, 0.0f);
    __syncthreads();
    if (c < 32) {
        const float* w = (c < 16) ? w_row : w_col;
        const int cc = c & 15;
        float acc = 0.0f;
        #pragma unroll 8
        for (int r = 0; r < 128; ++r) acc += sh[r] * w[r*CPC + cc];
        if (c < 16) rq[(size_t)n*CPC + cc] = acc;
        else        rk[(size_t)n*CPC + cc] = acc;
    }
}

// ---------------------------------------------------------------------------
// K2: pair conditioning + MLP residual + pl (bf16, 3 blocks).
//     (R7-measured version: direct per-thread writes; LDS staging regressed.)
// ---------------------------------------------------------------------------
__global__ __launch_bounds__(256) void k_pair(
    const float* __restrict__ pos, const int* __restrict__ uid,
    const float* __restrict__ rq, const float* __restrict__ rk,
    const float* __restrict__ w_ofs, const float* __restrict__ w_dist,
    const float* __restrict__ w_pm,
    const float* __restrict__ mlp1, const float* __restrict__ mlp2,
    const float* __restrict__ mlp3,
    const float* __restrict__ wln, const float* __restrict__ wpl,
    float* __restrict__ pair, short* __restrict__ plb)
{
    __shared__ float sm1[256], sm2[256], sm3[256], sofs[48], sdist[16], smask[16];
    __shared__ float swln[16], swpl[192];
    const int tid = threadIdx.x;
    sm1[tid] = mlp1[tid]; sm2[tid] = mlp2[tid]; sm3[tid] = mlp3[tid];
    if (tid < 48) sofs[tid] = w_ofs[tid];
    if (tid < 16) { sdist[tid] = w_dist[tid]; smask[tid] = w_pm[tid]; swln[tid] = wln[tid]; }
    if (tid < 192) swpl[tid] = wpl[tid];
    __syncthreads();

    const int gid = blockIdx.x*256 + tid;
    const int s = gid >> 12;
    const int rem = gid & 4095;
    const int q = rem >> 7, kk = rem & 127;
    const int n = s*QBQ + q;
    int kidx = s*QBQ - 48 + kk; kidx = max(0, min(NN-1, kidx));

    const float v = (uid[n] == uid[kidx]) ? 1.0f : 0.0f;
    const float o0 = pos[n*3+0]-pos[kidx*3+0];
    const float o1 = pos[n*3+1]-pos[kidx*3+1];
    const float o2 = pos[n*3+2]-pos[kidx*3+2];
    const float sq = o0*o0 + o1*o1 + o2*o2;
    const float inv = 1.0f/(1.0f + sq);

    const float* rqp = rq + (size_t)n*CPC;
    const float* rkp = rk + (size_t)kidx*CPC;

    float p[16], t1[16], t2[16];
    #pragma unroll
    for (int j = 0; j < 16; ++j)
        p[j] = v*(o0*sofs[j] + o1*sofs[16+j] + o2*sofs[32+j] + inv*sdist[j] + smask[j])
             + rqp[j] + rkp[j];
    #pragma unroll
    for (int j = 0; j < 16; ++j) {
        float acc = 0.0f;
        #pragma unroll
        for (int r = 0; r < 16; ++r) acc += fmaxf(p[r], 0.0f) * sm1[r*16+j];
        t1[j] = acc;
    }
    #pragma unroll
    for (int j = 0; j < 16; ++j) {
        float acc = 0.0f;
        #pragma unroll
        for (int r = 0; r < 16; ++r) acc += fmaxf(t1[r], 0.0f) * sm2[r*16+j];
        t2[j] = acc;
    }
    #pragma unroll
    for (int j = 0; j < 16; ++j) {
        float acc = 0.0f;
        #pragma unroll
        for (int r = 0; r < 16; ++r) acc += fmaxf(t2[r], 0.0f) * sm3[r*16+j];
        t1[j] = p[j] + acc;
    }
    float* op = pair + (size_t)gid*CPC;
    #pragma unroll
    for (int j = 0; j < 4; ++j)
        *(float4*)(op + j*4) = make_float4(t1[j*4], t1[j*4+1], t1[j*4+2], t1[j*4+3]);

    float sm = 0.0f;
    #pragma unroll
    for (int j = 0; j < 16; ++j) sm += t1[j];
    const float mu = sm * (1.0f/16.0f);
    float vq = 0.0f;
    #pragma unroll
    for (int j = 0; j < 16; ++j) { const float dd = t1[j]-mu; vq += dd*dd; }
    const float rs = rsqrtf(vq*(1.0f/16.0f) + 1e-5f);
    float xn[16];
    #pragma unroll
    for (int j = 0; j < 16; ++j) xn[j] = (t1[j]-mu)*rs*swln[j];
    #pragma unroll
    for (int i = 0; i < 3; ++i) {
        #pragma unroll
        for (int h = 0; h < 4; ++h) {
            float acc = 0.0f;
            #pragma unroll
            for (int j = 0; j < 16; ++j) acc += xn[j] * swpl[j*12 + i*4 + h];
            plb[((((size_t)i*SS + s)*HH + h)*QBQ + q)*KBK + kk] = f2bf(acc);
        }
    }
}

// ---------------------------------------------------------------------------
// K4: fused multi-job bf16 MFMA GEMM. MF = row-frags/wave; tile = MF*64 rows.
//   amode 0: A bf16 [M][K]
//   amode 1: A = bf16( G*((qact-mu)*rstd) + S )   (adaLN apply, K=128)
//   amode 2: A = bf16( Ao * Ag )                  (o*gate, K=128)
//   amode 3: A = bf16( fp32 A )                   (cast)
//   emode 0: out = acc (+bias); 1: sigmoid; 2: relu
//   emode 3: resid += acc*gate; write resid; emit per-row LN stats (mu,rstd)
//   emode 4: fused token reduce: token_o[t,col] = sum_a relu(acc)*m / max(sum m,eps)
// ---------------------------------------------------------------------------
struct FJob {
    const void* A; const void* A2;
    const float* stats; const short* G; const short* S;
    const short* Bt; const float* bias;
    float* outF; short* outB;
    const short* gate; float* resid; float* ostats;
    const float* msk;
    int K; int ostride; int amode; int emode;
};
struct FJobs { FJob j[8]; };

template<int MF>
__global__ __launch_bounds__(256) void k_mmf(FJobs jobs)
{
    __shared__ short As[MF*64*64];
    __shared__ short Bs[128*64];
    const FJob J = jobs.j[blockIdx.y];
    const int tid = threadIdx.x;
    const int wave = tid >> 6, lane = tid & 63;
    const int l15 = lane & 15, l4 = lane >> 4;
    const int row0 = blockIdx.x * (MF*64);
    const int K = J.K;

    f32x4 acc[MF][8];
    #pragma unroll
    for (int m = 0; m < MF; ++m)
        #pragma unroll
        for (int n = 0; n < 8; ++n) acc[m][n] = (f32x4){0.f,0.f,0.f,0.f};

    for (int k0 = 0; k0 < K; k0 += 64) {
        #pragma unroll
        for (int j = 0; j < MF*2; ++j) {
            const int u = tid + j*256;
            const int r = u >> 3, ug = u & 7;
            const int row = row0 + r;
            const size_t ao = (size_t)row*K + k0 + ug*8;
            bf16x8 av;
            if (J.amode == 0) {
                av = *(const bf16x8*)((const short*)J.A + ao);
            } else if (J.amode == 1) {
                const float* Af = (const float*)J.A;
                const float4 a0 = *(const float4*)(Af + ao);
                const float4 a1 = *(const float4*)(Af + ao + 4);
                const float mu = J.stats[2*row], rsd = J.stats[2*row+1];
                const s16x4 g0 = *(const s16x4*)(J.G + ao), g1 = *(const s16x4*)(J.G + ao + 4);
                const s16x4 s0 = *(const s16x4*)(J.S + ao), s1 = *(const s16x4*)(J.S + ao + 4);
                const float x[8] = {a0.x,a0.y,a0.z,a0.w,a1.x,a1.y,a1.z,a1.w};
                #pragma unroll
                for (int t = 0; t < 4; ++t) {
                    av[t]   = f2bf(b2f(g0[t])*((x[t]  -mu)*rsd) + b2f(s0[t]));
                    av[t+4] = f2bf(b2f(g1[t])*((x[t+4]-mu)*rsd) + b2f(s1[t]));
                }
            } else if (J.amode == 2) {
                const float* Ao = (const float*)J.A;
                const float* Ag = (const float*)J.A2;
                const float4 oa = *(const float4*)(Ao + ao);
                const float4 ob = *(const float4*)(Ao + ao + 4);
                const float4 ga = *(const float4*)(Ag + ao);
                const float4 gb = *(const float4*)(Ag + ao + 4);
                av[0]=f2bf(oa.x*ga.x); av[1]=f2bf(oa.y*ga.y); av[2]=f2bf(oa.z*ga.z); av[3]=f2bf(oa.w*ga.w);
                av[4]=f2bf(ob.x*gb.x); av[5]=f2bf(ob.y*gb.y); av[6]=f2bf(ob.z*gb.z); av[7]=f2bf(ob.w*gb.w);
            } else {
                const float* Af = (const float*)J.A;
                const float4 a0 = *(const float4*)(Af + ao);
                const float4 a1 = *(const float4*)(Af + ao + 4);
                av[0]=f2bf(a0.x); av[1]=f2bf(a0.y); av[2]=f2bf(a0.z); av[3]=f2bf(a0.w);
                av[4]=f2bf(a1.x); av[5]=f2bf(a1.y); av[6]=f2bf(a1.z); av[7]=f2bf(a1.w);
            }
            *(bf16x8*)&As[r*64 + ((ug ^ (r & 7)) * 8)] = av;
        }
        #pragma unroll
        for (int j = 0; j < 4; ++j) {
            const int u = tid + j*256;
            const int r = u >> 3, ug = u & 7;
            *(bf16x8*)&Bs[r*64 + ((ug ^ (r & 7)) * 8)] =
                *(const bf16x8*)(J.Bt + (size_t)r*K + k0 + ug*8);
        }
        __syncthreads();
        #pragma unroll
        for (int ks = 0; ks < 2; ++ks) {
            bf16x8 af[MF], bfr[8];
            #pragma unroll
            for (int m = 0; m < MF; ++m) {
                const int r = wave*(16*MF) + m*16 + l15;
                af[m] = *(const bf16x8*)&As[r*64 + (((ks*4 + l4) ^ (r & 7)) * 8)];
            }
            #pragma unroll
            for (int n = 0; n < 8; ++n) {
                const int c = n*16 + l15;
                bfr[n] = *(const bf16x8*)&Bs[c*64 + (((ks*4 + l4) ^ (c & 7)) * 8)];
            }
            #pragma unroll
            for (int m = 0; m < MF; ++m)
                #pragma unroll
                for (int n = 0; n < 8; ++n)
                    acc[m][n] = __builtin_amdgcn_mfma_f32_16x16x32_bf16(af[m], bfr[n], acc[m][n], 0, 0, 0);
        }
        __syncthreads();
    }

    if (J.emode == 3) {
        #pragma unroll
        for (int m = 0; m < MF; ++m) {
            #pragma unroll
            for (int reg = 0; reg < 4; ++reg) {
                const int row = row0 + wave*(16*MF) + m*16 + l4*4 + reg;
                float s = 0.0f, q = 0.0f;
                #pragma unroll
                for (int n = 0; n < 8; ++n) {
                    const int col = n*16 + l15;
                    const size_t off = (size_t)row*CAC + col;
                    const float v = J.resid[off] + acc[m][n][reg] * b2f(J.gate[off]);
                    J.resid[off] = v;
                    s += v; q += v*v;
                }
                #pragma unroll
                for (int msk_ = 1; msk_ < 16; msk_ <<= 1) {
                    s += __shfl_xor(s, msk_, 64);
                    q += __shfl_xor(q, msk_, 64);
                }
                if (l15 == 0) {
                    const float mu = s * (1.0f/128.0f);
                    const float var = q * (1.0f/128.0f) - mu*mu;
                    J.ostats[2*row]   = mu;
                    J.ostats[2*row+1] = rsqrtf(var + 1e-5f);
                }
            }
        }
    } else if (J.emode == 4) {
        #pragma unroll
        for (int m = 0; m < MF; ++m) {
            const int rbase = row0 + wave*(16*MF) + m*16 + l4*4;
            const int t = rbase >> 2;
            const float4 mv = *(const float4*)(J.msk + (size_t)rbase);
            const float den = fmaxf(mv.x + mv.y + mv.z + mv.w, 1e-10f);
            const float inv = 1.0f / den;
            #pragma unroll
            for (int n = 0; n < 8; ++n) {
                const int col = n*16 + l15;
                const float num = fmaxf(acc[m][n][0], 0.f)*mv.x
                                + fmaxf(acc[m][n][1], 0.f)*mv.y
                                + fmaxf(acc[m][n][2], 0.f)*mv.z
                                + fmaxf(acc[m][n][3], 0.f)*mv.w;
                J.outF[(size_t)t*J.ostride + col] = num * inv;
            }
        }
    } else {
        float bval[8];
        #pragma unroll
        for (int n = 0; n < 8; ++n) bval[n] = 0.0f;
        if (J.bias) {
            #pragma unroll
            for (int n = 0; n < 8; ++n) bval[n] = J.bias[n*16 + l15];
        }
        const int epi = J.emode;
        #pragma unroll
        for (int m = 0; m < MF; ++m) {
            #pragma unroll
            for (int n = 0; n < 8; ++n) {
                const int col = n*16 + l15;
                #pragma unroll
                for (int reg = 0; reg < 4; ++reg) {
                    const int row = row0 + wave*(16*MF) + m*16 + l4*4 + reg;
                    float v = acc[m][n][reg] + bval[n];
                    if (epi == 1) v = sig_(v);
                    if (epi == 2) v = fmaxf(v, 0.0f);
                    if (J.outB) J.outB[(size_t)row*J.ostride + col] = f2bf(v);
                    else        J.outF[(size_t)row*J.ostride + col] = v;
                }
            }
        }
    }
}

// ---------------------------------------------------------------------------
// K4c: SwiGLU GEMM, 64-row x 64-col tiles (grid 256 x 4 = 1024 blocks):
//      x = adaLN(Gt,St); hs = bf16(silu(x@glu1)*(x@glu2)).
// ---------------------------------------------------------------------------
__global__ __launch_bounds__(256) void k_mm_glu(
    const float* __restrict__ qact, const float* __restrict__ stats,
    const short* __restrict__ Gt, const short* __restrict__ St,
    const short* __restrict__ B1t, const short* __restrict__ B2t,
    short* __restrict__ out)
{
    __shared__ short As[64*64];
    __shared__ short B1s[64*64];
    __shared__ short B2s[64*64];
    const int tid = threadIdx.x;
    const int wave = tid >> 6, lane = tid & 63;
    const int l15 = lane & 15, l4 = lane >> 4;
    const int row0 = blockIdx.x * 64;
    const int col0 = blockIdx.y * 64;

    f32x4 acc1[4], acc2[4];
    #pragma unroll
    for (int n = 0; n < 4; ++n) {
        acc1[n] = (f32x4){0.f,0.f,0.f,0.f};
        acc2[n] = (f32x4){0.f,0.f,0.f,0.f};
    }

    for (int k0 = 0; k0 < 128; k0 += 64) {
        #pragma unroll
        for (int j = 0; j < 2; ++j) {
            const int u = tid + j*256;
            const int r = u >> 3, ug = u & 7;
            const int row = row0 + r;
            const size_t ao = (size_t)row*CAC + k0 + ug*8;
            const float4 a0 = *(const float4*)(qact + ao);
            const float4 a1 = *(const float4*)(qact + ao + 4);
            const float mu = stats[2*row], rsd = stats[2*row+1];
            const s16x4 g0 = *(const s16x4*)(Gt + ao), g1 = *(const s16x4*)(Gt + ao + 4);
            const s16x4 s0 = *(const s16x4*)(St + ao), s1 = *(const s16x4*)(St + ao + 4);
            const float x[8] = {a0.x,a0.y,a0.z,a0.w,a1.x,a1.y,a1.z,a1.w};
            bf16x8 av;
            #pragma unroll
            for (int t = 0; t < 4; ++t) {
                av[t]   = f2bf(b2f(g0[t])*((x[t]  -mu)*rsd) + b2f(s0[t]));
                av[t+4] = f2bf(b2f(g1[t])*((x[t+4]-mu)*rsd) + b2f(s1[t]));
            }
            const int sw = (ug ^ (r & 7)) * 8;
            *(bf16x8*)&As[r*64 + sw] = av;
            const size_t bo = (size_t)(col0 + r)*CAC + k0 + ug*8;
            *(bf16x8*)&B1s[r*64 + sw] = *(const bf16x8*)(B1t + bo);
            *(bf16x8*)&B2s[r*64 + sw] = *(const bf16x8*)(B2t + bo);
        }
        __syncthreads();
        #pragma unroll
        for (int ks = 0; ks < 2; ++ks) {
            bf16x8 af, b1f[4], b2f_[4];
            {
                const int r = wave*16 + l15;
                af = *(const bf16x8*)&As[r*64 + (((ks*4 + l4) ^ (r & 7)) * 8)];
            }
            #pragma unroll
            for (int n = 0; n < 4; ++n) {
                const int c = n*16 + l15;
                const int sw = ((ks*4 + l4) ^ (c & 7)) * 8;
                b1f[n] = *(const bf16x8*)&B1s[c*64 + sw];
                b2f_[n] = *(const bf16x8*)&B2s[c*64 + sw];
            }
            #pragma unroll
            for (int n = 0; n < 4; ++n) {
                acc1[n] = __builtin_amdgcn_mfma_f32_16x16x32_bf16(af, b1f[n], acc1[n], 0, 0, 0);
                acc2[n] = __builtin_amdgcn_mfma_f32_16x16x32_bf16(af, b2f_[n], acc2[n], 0, 0, 0);
            }
        }
        __syncthreads();
    }

    #pragma unroll
    for (int n = 0; n < 4; ++n) {
        const int col = col0 + n*16 + l15;
        #pragma unroll
        for (int reg = 0; reg < 4; ++reg) {
            const int row = row0 + wave*16 + l4*4 + reg;
            const float a1 = acc1[n][reg];
            out[(size_t)row*256 + col] = f2bf(a1 * sig_(a1) * acc2[n][reg]);
        }
    }
}

// ---------------------------------------------------------------------------
// K5: flash attention (pl in bf16)
// ---------------------------------------------------------------------------
__global__ __launch_bounds__(512) void k_attn2(
    const float* __restrict__ qh, const float* __restrict__ kh,
    const float* __restrict__ vh, const short* __restrict__ pls,
    float* __restrict__ oh)
{
    __shared__ float sm_m[256], sm_l[256], sm_acc[256*17];
    const int s = blockIdx.x, tid = threadIdx.x;
    const int kh2 = tid >> 8;
    const int h = (tid >> 6) & 3;
    const int q = (tid >> 1) & 31;
    const int dh = tid & 1;
    const int n0 = s*QBQ;
    const int kbase = n0 - 48 + kh2*64;
    const float SCALE = 0.17677669529663687f;

    float qr[32];
    {
        const float* qp = qh + (size_t)(n0+q)*CAC + h*DKD;
        #pragma unroll
        for (int j = 0; j < 8; ++j) {
            const float4 v4 = *(const float4*)(qp + j*4);
            qr[j*4]=v4.x*SCALE; qr[j*4+1]=v4.y*SCALE; qr[j*4+2]=v4.z*SCALE; qr[j*4+3]=v4.w*SCALE;
        }
    }
    const short* plp = pls + (((size_t)s*HH + h)*QBQ + q)*KBK + kh2*64;

    float m = -1e30f, l = 0.0f;
    float acc[16];
    #pragma unroll
    for (int j = 0; j < 16; ++j) acc[j] = 0.0f;

    for (int kb4 = 0; kb4 < 16; ++kb4) {
        const s16x4 p4 = *(const s16x4*)(plp + kb4*4);
        float pv[4];
        #pragma unroll
        for (int j = 0; j < 4; ++j) pv[j] = b2f(p4[j]);
        #pragma unroll
        for (int j = 0; j < 4; ++j) {
            const int kb = kb4*4 + j;
            int kidx = kbase + kb; kidx = max(0, min(NN-1, kidx));
            const float* kp = kh + (size_t)kidx*CAC + h*DKD;
            float dot = 0.0f;
            #pragma unroll
            for (int jj = 0; jj < 8; ++jj) {
                const float4 kv = *(const float4*)(kp + jj*4);
                dot += qr[jj*4]*kv.x + qr[jj*4+1]*kv.y + qr[jj*4+2]*kv.z + qr[jj*4+3]*kv.w;
            }
            const float sv = dot + pv[j];
            if (sv > m) {
                const float corr = __expf(m - sv);
                l *= corr;
                #pragma unroll
                for (int d = 0; d < 16; ++d) acc[d] *= corr;
                m = sv;
            }
            const float w = __expf(sv - m);
            l += w;
            const float* vp = vh + (size_t)kidx*CAC + h*DKD + dh*16;
            #pragma unroll
            for (int jj = 0; jj < 4; ++jj) {
                const float4 vv = *(const float4*)(vp + jj*4);
                acc[jj*4]   = fmaf(w, vv.x, acc[jj*4]);
                acc[jj*4+1] = fmaf(w, vv.y, acc[jj*4+1]);
                acc[jj*4+2] = fmaf(w, vv.z, acc[jj*4+2]);
                acc[jj*4+3] = fmaf(w, vv.w, acc[jj*4+3]);
            }
        }
    }

    const int part = tid & 255;
    if (kh2 == 1) {
        sm_m[part] = m; sm_l[part] = l;
        #pragma unroll
        for (int j = 0; j < 16; ++j) sm_acc[part*17 + j] = acc[j];
    }
    __syncthreads();
    if (kh2 == 0) {
        const float m2 = sm_m[part], l2 = sm_l[part];
        const float mm = fmaxf(m, m2);
        const float c1 = __expf(m - mm), c2 = __expf(m2 - mm);
        const float inv = 1.0f / (l*c1 + l2*c2);
        float* op = oh + (size_t)(n0+q)*CAC + h*DKD + dh*16;
        #pragma unroll
        for (int jj = 0; jj < 4; ++jj) {
            float o0 = (acc[jj*4  ]*c1 + sm_acc[part*17+jj*4  ]*c2) * inv;
            float o1 = (acc[jj*4+1]*c1 + sm_acc[part*17+jj*4+1]*c2) * inv;
            float o2 = (acc[jj*4+2]*c1 + sm_acc[part*17+jj*4+2]*c2) * inv;
            float o3 = (acc[jj*4+3]*c1 + sm_acc[part*17+jj*4+3]*c2) * inv;
            *(float4*)op = make_float4(o0,o1,o2,o3);
            op += 4;
        }
    }
}

// ---------------------------------------------------------------------------
// launch
// ---------------------------------------------------------------------------
static inline FJob fj0() { FJob j{}; return j; }

extern "C" void kernel_launch(void* const* d_in, const int* in_sizes, int n_in,
                              void* d_out, int out_size, void* d_ws, size_t ws_size,
                              hipStream_t stream)
{
    const float* positions = (const float*)d_in[0];
    const float* maskp     = (const float*)d_in[1];
    const int*   element   = (const int*  )d_in[2];
    const float* charge    = (const float*)d_in[3];
    const int*   chars     = (const int*  )d_in[4];
    const int*   uid       = (const int*  )d_in[5];
    const float* w_ref_pos      = (const float*)d_in[6];
    const float* w_ref_mask     = (const float*)d_in[7];
    const float* w_ref_element  = (const float*)d_in[8];
    const float* w_ref_charge   = (const float*)d_in[9];
    const float* w_ref_atom_name= (const float*)d_in[10];
    const float* w_s2p_row      = (const float*)d_in[11];
    const float* w_s2p_col      = (const float*)d_in[12];
    const float* w_pair_offsets = (const float*)d_in[13];
    const float* w_pair_dist    = (const float*)d_in[14];
    const float* w_pair_mask    = (const float*)d_in[15];
    const float* w_pair_mlp1    = (const float*)d_in[16];
    const float* w_pair_mlp2    = (const float*)d_in[17];
    const float* w_pair_mlp3    = (const float*)d_in[18];
    const float* w_pair_ln      = (const float*)d_in[19];
    const float* w_pair_logits  = (const float*)d_in[20];
    const float* aq_lnw = (const float*)d_in[21];
    const float* aq_gw  = (const float*)d_in[22];
    const float* aq_gb  = (const float*)d_in[23];
    const float* aq_sw  = (const float*)d_in[24];
    const float* ak_lnw = (const float*)d_in[25];
    const float* ak_gw  = (const float*)d_in[26];
    const float* ak_gb  = (const float*)d_in[27];
    const float* ak_sw  = (const float*)d_in[28];
    const float* wq     = (const float*)d_in[29];
    const float* bq     = (const float*)d_in[30];
    const float* wk     = (const float*)d_in[31];
    const float* wv     = (const float*)d_in[32];
    const float* wg     = (const float*)d_in[33];
    const float* azi_w  = (const float*)d_in[34];
    const float* azi_cw = (const float*)d_in[35];
    const float* azi_cb = (const float*)d_in[36];
    const float* t_lnw  = (const float*)d_in[37];
    const float* t_gw   = (const float*)d_in[38];
    const float* t_gb   = (const float*)d_in[39];
    const float* t_sw   = (const float*)d_in[40];
    const float* glu1   = (const float*)d_in[41];
    const float* glu2   = (const float*)d_in[42];
    const float* t_azi_w  = (const float*)d_in[43];
    const float* t_azi_cw = (const float*)d_in[44];
    const float* t_azi_cb = (const float*)d_in[45];
    const float* w_project= (const float*)d_in[46];

    float* token_o = (float*)d_out;
    float* qact = token_o + 1572864;
    float* qsc  = token_o + 3670016;
    float* pair = token_o + 5767168;

    char* W = (char*)d_ws;
    short* pl_bf   = (short*)(W);                 // 50,331,648
    short* wbf     = (short*)(W + 50331648);      //  2,097,152
    short* qn_bf   = (short*)(W + 52428800);      //  4,194,304
    short* qsc_bf  = (short*)(W + 56623104);      //  4,194,304
    float* stats   = (float*)(W + 60817408);      //    131,072
    short* Gq_bf   = (short*)(W + 60948480);
    short* Sq_bf   = (short*)(W + 65142784);
    short* Gk_bf   = (short*)(W + 69337088);
    short* Sk_bf   = (short*)(W + 73531392);
    short* Gt_bf   = (short*)(W + 77725696);
    short* St_bf   = (short*)(W + 81920000);
    short* Ag_bf   = (short*)(W + 86114304);
    short* Tg_bf   = (short*)(W + 90308608);
    float* w_q     = (float*)(W + 94502912);
    float* w_k     = (float*)(W + 102891520);
    float* w_v     = (float*)(W + 111280128);
    float* w_g     = (float*)(W + 119668736);
    float* w_o     = (float*)(W + 128057344);
    short* hs_bf   = (short*)(W + 136445952);
    float* rq      = (float*)(W + 144834560);
    float* rk      = (float*)(W + 145883136);

    (void)in_sizes; (void)n_in; (void)out_size; (void)ws_size;

    const size_t LSTR = 311296;
    const size_t oGQ=0, oSQ=16384, oGK=32768, oSK=49152, oGT=65536, oST=81920,
                 oWQ=98304, oWK=114688, oWV=131072, oWG=147456, oAZ=163840,
                 oACW=180224, oTCW=196608, oG1=212992, oG2=245760, oTAW=278528;
    const size_t oPROJ = 3*LSTR;

    {   // ---- weight prep ----
        PTab tab{};
        int e = 0;
        for (int i = 0; i < 3; ++i) {
            short* L = wbf + (size_t)i*LSTR;
            const size_t oM = (size_t)i*CAC*CAC, oV = (size_t)i*CAC, oGL = (size_t)i*CAC*2*CAC;
            tab.e[e++] = {aq_gw+oM,  aq_lnw+oV, L+oGQ,  128, 128};
            tab.e[e++] = {aq_sw+oM,  aq_lnw+oV, L+oSQ,  128, 128};
            tab.e[e++] = {ak_gw+oM,  ak_lnw+oV, L+oGK,  128, 128};
            tab.e[e++] = {ak_sw+oM,  ak_lnw+oV, L+oSK,  128, 128};
            tab.e[e++] = {t_gw+oM,   t_lnw+oV,  L+oGT,  128, 128};
            tab.e[e++] = {t_sw+oM,   t_lnw+oV,  L+oST,  128, 128};
            tab.e[e++] = {wq+oM,     nullptr,   L+oWQ,  128, 128};
            tab.e[e++] = {wk+oM,     nullptr,   L+oWK,  128, 128};
            tab.e[e++] = {wv+oM,     nullptr,   L+oWV,  128, 128};
            tab.e[e++] = {wg+oM,     nullptr,   L+oWG,  128, 128};
            tab.e[e++] = {azi_w+oM,  nullptr,   L+oAZ,  128, 128};
            tab.e[e++] = {azi_cw+oM, nullptr,   L+oACW, 128, 128};
            tab.e[e++] = {t_azi_cw+oM,nullptr,  L+oTCW, 128, 128};
            tab.e[e++] = {glu1+oGL,  nullptr,   L+oG1,  128, 256};
            tab.e[e++] = {glu2+oGL,  nullptr,   L+oG2,  128, 256};
            tab.e[e++] = {t_azi_w+oGL,nullptr,  L+oTAW, 256, 128};
        }
        tab.e[e++] = {w_project, nullptr, wbf+oPROJ, 128, 384};
        k_prep<<<dim3(48, 49), 256, 0, stream>>>(tab);
    }

    k_atom_cond<<<NN, 128, 0, stream>>>(positions, maskp, element, charge, chars,
        w_ref_pos, w_ref_mask, w_ref_element, w_ref_charge, w_ref_atom_name,
        w_s2p_row, w_s2p_col, qsc, qact, qsc_bf, qn_bf, stats, rq, rk);

    k_pair<<<(SS*QBQ*KBK)/256, 256, 0, stream>>>(positions, uid, rq, rk,
        w_pair_offsets, w_pair_dist, w_pair_mask, w_pair_mlp1, w_pair_mlp2, w_pair_mlp3,
        w_pair_ln, w_pair_logits, pair, pl_bf);

    for (int i = 0; i < 3; ++i) {
        short* L = wbf + (size_t)i*LSTR;
        const size_t oV = (size_t)i*CAC;

        {   // cond-only GEMMs (8 jobs, amode0): gates for this layer
            FJobs js{};
            struct { const short* A; const short* Bt; const float* bias; short* out; int em; } cfg[8] = {
                {qn_bf,  L+oGQ,  aq_gb+oV,    Gq_bf, 1}, {qn_bf,  L+oSQ,  nullptr, Sq_bf, 0},
                {qn_bf,  L+oGK,  ak_gb+oV,    Gk_bf, 1}, {qn_bf,  L+oSK,  nullptr, Sk_bf, 0},
                {qn_bf,  L+oGT,  t_gb+oV,     Gt_bf, 1}, {qn_bf,  L+oST,  nullptr, St_bf, 0},
                {qsc_bf, L+oACW, azi_cb+oV,   Ag_bf, 1}, {qsc_bf, L+oTCW, t_azi_cb+oV, Tg_bf, 1}};
            for (int jn = 0; jn < 8; ++jn) {
                FJob j = fj0();
                j.A = cfg[jn].A; j.Bt = cfg[jn].Bt; j.bias = cfg[jn].bias;
                j.outB = cfg[jn].out; j.K = 128; j.ostride = 128;
                j.amode = 0; j.emode = cfg[jn].em;
                js.j[jn] = j;
            }
            k_mmf<1><<<dim3(256, 8), 256, 0, stream>>>(js);
        }
        {   // q,k,v,g projections with fused adaLN A-staging (amode1)
            FJobs js{};
            struct { const short* G; const short* S; const short* Bt; const float* bias; float* out; int em; } cfg[4] = {
                {Gq_bf, Sq_bf, L+oWQ, bq+oV,   w_q, 0}, {Gk_bf, Sk_bf, L+oWK, nullptr, w_k, 0},
                {Gk_bf, Sk_bf, L+oWV, nullptr, w_v, 0}, {Gq_bf, Sq_bf, L+oWG, nullptr, w_g, 1}};
            for (int jn = 0; jn < 4; ++jn) {
                FJob j = fj0();
                j.A = qact; j.stats = stats; j.G = cfg[jn].G; j.S = cfg[jn].S;
                j.Bt = cfg[jn].Bt; j.bias = cfg[jn].bias; j.outF = cfg[jn].out;
                j.K = 128; j.ostride = 128; j.amode = 1; j.emode = cfg[jn].em;
                js.j[jn] = j;
            }
            k_mmf<1><<<dim3(256, 4), 256, 0, stream>>>(js);
        }
        k_attn2<<<SS, 512, 0, stream>>>(w_q, w_k, w_v, pl_bf + (size_t)i*8388608, w_o);
        {   // o-projection: A=o*g fused (amode2); epilogue residual+stats (emode3)
            FJobs js{};
            FJob j = fj0();
            j.A = w_o; j.A2 = w_g; j.Bt = L+oAZ;
            j.gate = Ag_bf; j.resid = qact; j.ostats = stats;
            j.K = 128; j.ostride = 128; j.amode = 2; j.emode = 3;
            js.j[0] = j;
            k_mmf<1><<<dim3(256, 1), 256, 0, stream>>>(js);
        }
        // SwiGLU (fused adaLN staging + silu*mul epilogue), 64x64 tiles
        k_mm_glu<<<dim3(256, 4), 256, 0, stream>>>(qact, stats, Gt_bf, St_bf, L+oG1, L+oG2, hs_bf);
        {   // transition out-projection (K=256); epilogue residual+stats
            FJobs js{};
            FJob j = fj0();
            j.A = hs_bf; j.Bt = L+oTAW;
            j.gate = Tg_bf; j.resid = qact; j.ostats = stats;
            j.K = 256; j.ostride = 128; j.amode = 0; j.emode = 3;
            js.j[0] = j;
            k_mmf<1><<<dim3(256, 1), 256, 0, stream>>>(js);
        }
    }

    {   // token projection with fused relu + masked-mean epilogue (emode 4)
        FJobs js{};
        for (int c = 0; c < 3; ++c) {
            FJob j = fj0();
            j.A = qact; j.Bt = wbf + oPROJ + (size_t)c*16384;
            j.outF = token_o + c*128; j.msk = maskp;
            j.K = 128; j.ostride = CTC; j.amode = 3; j.emode = 4;
            js.j[c] = j;
        }
        k_mmf<1><<<dim3(256, 3), 256, 0, stream>>>(js);
    }
}